// Round 1
// baseline (308.597 us; speedup 1.0000x reference)
//
#include <hip/hip_runtime.h>

#define E_    8
#define D_    2048
#define H_    1024
#define TWOH  2048
#define T_    2048   // B*L tokens
#define BM    128
#define BK    64
#define LDAP  72     // padded LDS row stride in bf16 elems (144 B = 16B-aligned, breaks pow2 stride)

using u16   = unsigned short;
using s16x8 = __attribute__((ext_vector_type(8))) short;
using s16x4 = __attribute__((ext_vector_type(4))) short;
using f32x4 = __attribute__((ext_vector_type(4))) float;

__device__ __forceinline__ u16 f2bf(float f) {
  union { float f; unsigned u; } v; v.f = f;
  unsigned r = v.u + 0x7fffu + ((v.u >> 16) & 1u);   // RNE
  return (u16)(r >> 16);
}

// ---------------- workspace layout (bytes) ----------------
// xb     : T*D bf16          =  8,388,608   @ 0
// a_buf  : E*T*H bf16        = 33,554,432   @ 8,388,608
// eo     : T*K*D f32         = 33,554,432   @ 41,943,040
// lists  : E*T int           =     65,536   @ 75,497,472
// gates  : T*K f32           =     16,384   @ 75,563,008
// counts : E int             =         32   @ 75,579,392
// total ~75.6 MB

__global__ __launch_bounds__(64) void zero_counts_kernel(int* counts) {
  if (threadIdx.x < E_) counts[threadIdx.x] = 0;
}

// one block per token: logits over 8 experts, top-2 + softmax, build lists,
// and convert the x row to bf16 (fused since we read the row anyway)
__global__ __launch_bounds__(256) void router_kernel(
    const float* __restrict__ x, const float* __restrict__ wg,
    u16* __restrict__ xb, int* __restrict__ lists, float* __restrict__ gates,
    int* __restrict__ counts)
{
  int t = blockIdx.x;
  int tid = threadIdx.x;
  const float* xr = x + (size_t)t * D_;
  float acc[E_];
#pragma unroll
  for (int e = 0; e < E_; ++e) acc[e] = 0.f;
#pragma unroll
  for (int i = 0; i < D_ / 256; ++i) {
    int d = tid + 256 * i;
    float xv = xr[d];
    xb[(size_t)t * D_ + d] = f2bf(xv);
#pragma unroll
    for (int e = 0; e < E_; ++e) acc[e] += xv * wg[e * D_ + d];
  }
#pragma unroll
  for (int off = 32; off >= 1; off >>= 1)
#pragma unroll
    for (int e = 0; e < E_; ++e) acc[e] += __shfl_down(acc[e], off);

  __shared__ float red[4][E_];
  int w = tid >> 6, lane = tid & 63;
  if (lane == 0)
#pragma unroll
    for (int e = 0; e < E_; ++e) red[w][e] = acc[e];
  __syncthreads();
  if (tid == 0) {
    float v0 = -1e30f, v1 = -1e30f; int e0 = 0, e1 = 0;
#pragma unroll
    for (int e = 0; e < E_; ++e) {
      float v = red[0][e] + red[1][e] + red[2][e] + red[3][e];
      if (v > v0)      { v1 = v0; e1 = e0; v0 = v; e0 = e; }
      else if (v > v1) { v1 = v;  e1 = e; }
    }
    float g1 = expf(v1 - v0);       // stable 2-way softmax
    float inv = 1.f / (1.f + g1);
    float g0 = inv; g1 *= inv;
    int s0 = atomicAdd(&counts[e0], 1);
    lists[e0 * T_ + s0] = t * 2 + 0;
    gates[t * 2 + 0] = g0;
    int s1 = atomicAdd(&counts[e1], 1);
    lists[e1 * T_ + s1] = t * 2 + 1;
    gates[t * 2 + 1] = g1;
  }
}

// grouped GEMM1 + SiLU-GLU epilogue.
// Block: 128 gathered token-rows x 128 h-cols where cols 0..63 = h1[bn*64..],
// cols 64..127 = h2[H + bn*64..] -> silu(h1)*h2 pairs in same lane/reg.
__global__ __launch_bounds__(256) void gemm1_kernel(
    const u16* __restrict__ xb, const float* __restrict__ w_in,
    const int* __restrict__ lists, const int* __restrict__ counts,
    u16* __restrict__ a_buf)
{
  int e = blockIdx.z, bm = blockIdx.y, bn = blockIdx.x;
  int Ne = counts[e];
  if (bm * BM >= Ne) return;

  __shared__ __align__(16) u16 As[BM][LDAP];
  __shared__ __align__(16) u16 Bs[BM][LDAP];

  int tid = threadIdx.x;
  int w = tid >> 6, lane = tid & 63;

  // A staging: chunk c = tid + 256*i (i<4); row = (tid>>3)+32i, kchunk = tid&7 (8 bf16)
  int arow = tid >> 3, akc = tid & 7;
  int tok[4];
#pragma unroll
  for (int i = 0; i < 4; ++i) {
    int gr = bm * BM + arow + 32 * i;
    tok[i] = (gr < Ne) ? (lists[e * T_ + gr] >> 1) : -1;
  }
  // B staging: c = tid + 256*i (i<8); row = (tid>>4)+16i, fchunk = tid&15 (4 f32)
  int brow = tid >> 4, bfc = tid & 15;
  const float* we = w_in + (size_t)e * TWOH * D_;

  f32x4 acc[2][8];
#pragma unroll
  for (int m = 0; m < 2; ++m)
#pragma unroll
    for (int n = 0; n < 8; ++n) acc[m][n] = (f32x4){0.f, 0.f, 0.f, 0.f};

  for (int k0 = 0; k0 < D_; k0 += BK) {
#pragma unroll
    for (int i = 0; i < 4; ++i) {
      int r = arow + 32 * i;
      s16x8 v = {0, 0, 0, 0, 0, 0, 0, 0};
      if (tok[i] >= 0)
        v = *(const s16x8*)(xb + (size_t)tok[i] * D_ + k0 + akc * 8);
      *(s16x8*)(&As[r][akc * 8]) = v;
    }
#pragma unroll
    for (int i = 0; i < 8; ++i) {
      int r = brow + 16 * i;
      int o = (r < 64) ? (bn * 64 + r) : (H_ + bn * 64 + (r - 64));
      f32x4 f = *(const f32x4*)(we + (size_t)o * D_ + k0 + bfc * 4);
      s16x4 bv = {(short)f2bf(f.x), (short)f2bf(f.y), (short)f2bf(f.z), (short)f2bf(f.w)};
      *(s16x4*)(&Bs[r][bfc * 4]) = bv;
    }
    __syncthreads();
#pragma unroll
    for (int ks = 0; ks < 2; ++ks) {
      int lrow = lane & 15, lk = ks * 32 + (lane >> 4) * 8;
      s16x8 af[2], bf[8];
#pragma unroll
      for (int m = 0; m < 2; ++m)
        af[m] = *(const s16x8*)(&As[w * 32 + m * 16 + lrow][lk]);
#pragma unroll
      for (int n = 0; n < 8; ++n)
        bf[n] = *(const s16x8*)(&Bs[n * 16 + lrow][lk]);
#pragma unroll
      for (int m = 0; m < 2; ++m)
#pragma unroll
        for (int n = 0; n < 8; ++n)
          acc[m][n] = __builtin_amdgcn_mfma_f32_16x16x32_bf16(af[m], bf[n], acc[m][n], 0, 0, 0);
    }
    __syncthreads();
  }
  // epilogue: a = silu(h1) * h2, store bf16
  int lcol = lane & 15, lr4 = (lane >> 4) * 4;
#pragma unroll
  for (int m = 0; m < 2; ++m)
#pragma unroll
    for (int n = 0; n < 4; ++n)
#pragma unroll
      for (int r = 0; r < 4; ++r) {
        int row = bm * BM + w * 32 + m * 16 + lr4 + r;
        if (row < Ne) {
          float h1 = acc[m][n][r], h2 = acc[m][n + 4][r];
          float a = (h1 / (1.f + expf(-h1))) * h2;
          int col = bn * 64 + n * 16 + lcol;
          a_buf[((size_t)e * T_ + row) * H_ + col] = f2bf(a);
        }
      }
}

// grouped GEMM2: eo[p] = gate[p] * (a_row . w_out[e]^T), scattered by pair id
__global__ __launch_bounds__(256) void gemm2_kernel(
    const u16* __restrict__ a_buf, const float* __restrict__ w_out,
    const int* __restrict__ lists, const int* __restrict__ counts,
    const float* __restrict__ gates, float* __restrict__ eo)
{
  int e = blockIdx.z, bm = blockIdx.y, bn = blockIdx.x;
  int Ne = counts[e];
  if (bm * BM >= Ne) return;

  __shared__ __align__(16) u16 As[BM][LDAP];
  __shared__ __align__(16) u16 Bs[BM][LDAP];

  int tid = threadIdx.x;
  int w = tid >> 6, lane = tid & 63;
  int arow = tid >> 3, akc = tid & 7;
  int brow = tid >> 4, bfc = tid & 15;
  const float* we = w_out + (size_t)e * D_ * H_;

  f32x4 acc[2][8];
#pragma unroll
  for (int m = 0; m < 2; ++m)
#pragma unroll
    for (int n = 0; n < 8; ++n) acc[m][n] = (f32x4){0.f, 0.f, 0.f, 0.f};

  for (int k0 = 0; k0 < H_; k0 += BK) {
#pragma unroll
    for (int i = 0; i < 4; ++i) {
      int r = arow + 32 * i;
      int gr = bm * BM + r;
      s16x8 v = {0, 0, 0, 0, 0, 0, 0, 0};
      if (gr < Ne)
        v = *(const s16x8*)(a_buf + ((size_t)e * T_ + gr) * H_ + k0 + akc * 8);
      *(s16x8*)(&As[r][akc * 8]) = v;
    }
#pragma unroll
    for (int i = 0; i < 8; ++i) {
      int r = brow + 16 * i;
      int o = bn * BM + r;                      // output d-column
      f32x4 f = *(const f32x4*)(we + (size_t)o * H_ + k0 + bfc * 4);
      s16x4 bv = {(short)f2bf(f.x), (short)f2bf(f.y), (short)f2bf(f.z), (short)f2bf(f.w)};
      *(s16x4*)(&Bs[r][bfc * 4]) = bv;
    }
    __syncthreads();
#pragma unroll
    for (int ks = 0; ks < 2; ++ks) {
      int lrow = lane & 15, lk = ks * 32 + (lane >> 4) * 8;
      s16x8 af[2], bf[8];
#pragma unroll
      for (int m = 0; m < 2; ++m)
        af[m] = *(const s16x8*)(&As[w * 32 + m * 16 + lrow][lk]);
#pragma unroll
      for (int n = 0; n < 8; ++n)
        bf[n] = *(const s16x8*)(&Bs[n * 16 + lrow][lk]);
#pragma unroll
      for (int m = 0; m < 2; ++m)
#pragma unroll
        for (int n = 0; n < 8; ++n)
          acc[m][n] = __builtin_amdgcn_mfma_f32_16x16x32_bf16(af[m], bf[n], acc[m][n], 0, 0, 0);
    }
    __syncthreads();
  }
  int lcol = lane & 15, lr4 = (lane >> 4) * 4;
#pragma unroll
  for (int m = 0; m < 2; ++m)
#pragma unroll
    for (int r = 0; r < 4; ++r) {
      int row = bm * BM + w * 32 + m * 16 + lr4 + r;
      if (row < Ne) {
        int p = lists[e * T_ + row];
        float g = gates[p];
#pragma unroll
        for (int n = 0; n < 8; ++n) {
          int col = bn * BM + n * 16 + lcol;
          eo[(size_t)p * D_ + col] = g * acc[m][n][r];
        }
      }
    }
}

__global__ __launch_bounds__(256) void finalize_kernel(
    const float* __restrict__ eo, const float* __restrict__ bias,
    float* __restrict__ out)
{
  int idx = blockIdx.x * 256 + threadIdx.x;       // one float4 per thread
  int t = idx / (D_ / 4);
  int dq = idx % (D_ / 4);
  f32x4 a = *(const f32x4*)(eo + (size_t)(t * 2) * D_ + dq * 4);
  f32x4 b = *(const f32x4*)(eo + (size_t)(t * 2 + 1) * D_ + dq * 4);
  f32x4 c = *(const f32x4*)(bias + dq * 4);
  f32x4 y = a + b + c;
  *(f32x4*)(out + (size_t)t * D_ + dq * 4) = y;
  if (idx == 0) out[(size_t)T_ * D_] = 0.0f;      // router aux loss (eval mode)
}

extern "C" void kernel_launch(void* const* d_in, const int* in_sizes, int n_in,
                              void* d_out, int out_size, void* d_ws, size_t ws_size,
                              hipStream_t stream)
{
  const float* x      = (const float*)d_in[0];
  const float* w_gate = (const float*)d_in[1];
  const float* w_in   = (const float*)d_in[2];
  const float* w_out  = (const float*)d_in[3];
  const float* bias   = (const float*)d_in[4];
  float* out = (float*)d_out;

  char* ws = (char*)d_ws;
  u16*   xb     = (u16*)(ws);
  u16*   a_buf  = (u16*)(ws + 8388608);
  float* eo     = (float*)(ws + 41943040);
  int*   lists  = (int*)(ws + 75497472);
  float* gates  = (float*)(ws + 75563008);
  int*   counts = (int*)(ws + 75579392);

  zero_counts_kernel<<<1, 64, 0, stream>>>(counts);
  router_kernel<<<T_, 256, 0, stream>>>(x, w_gate, xb, lists, gates, counts);
  dim3 g1(H_ / 64, T_ / BM, E_);    // (16, 16, 8), most bm-tiles early-exit
  gemm1_kernel<<<g1, 256, 0, stream>>>(xb, w_in, lists, counts, a_buf);
  dim3 g2(D_ / BM, T_ / BM, E_);    // (16, 16, 8)
  gemm2_kernel<<<g2, 256, 0, stream>>>(a_buf, w_out, lists, counts, gates, eo);
  finalize_kernel<<<(T_ * D_ / 4) / 256, 256, 0, stream>>>(eo, bias, out);
}

// Round 2
// 306.942 us; speedup vs baseline: 1.0054x; 1.0054x over previous
//
#include <hip/hip_runtime.h>

#define E_    8
#define D_    2048
#define H_    1024
#define T_    2048   // B*L tokens
#define BK    64

using u16   = unsigned short;
using s16x8 = __attribute__((ext_vector_type(8))) short;
using f32x4 = __attribute__((ext_vector_type(4))) float;

__device__ __forceinline__ u16 f2bf(float f) {
  union { float f; unsigned u; } v; v.f = f;
  unsigned r = v.u + 0x7fffu + ((v.u >> 16) & 1u);   // RNE
  return (u16)(r >> 16);
}
__device__ __forceinline__ s16x8 cvt8(f32x4 a, f32x4 b) {
  s16x8 o;
  o[0]=(short)f2bf(a.x); o[1]=(short)f2bf(a.y); o[2]=(short)f2bf(a.z); o[3]=(short)f2bf(a.w);
  o[4]=(short)f2bf(b.x); o[5]=(short)f2bf(b.y); o[6]=(short)f2bf(b.z); o[7]=(short)f2bf(b.w);
  return o;
}
// swizzled LDS slot (elem index) for (row, 8-elem chunk) in a [128][64] bf16 tile
__device__ __forceinline__ int slot(int r, int c) { return r * 64 + ((c ^ (r & 7)) << 3); }

// ---------------- workspace layout (bytes) ----------------
// xb     : T*D bf16     =  8,388,608  @ 0
// a_buf  : E*T*H bf16   = 33,554,432  @ 8,388,608
// lists  : E*T int      =     65,536  @ 41,943,040
// gates  : T*K f32      =     16,384  @ 42,008,576
// counts : E int        =         32  @ 42,024,960

// fill out with bias (gemm2 atomically accumulates on top), zero loss + counts
__global__ __launch_bounds__(256) void init_kernel(
    const float* __restrict__ bias, float* __restrict__ out, int* __restrict__ counts)
{
  int idx = blockIdx.x * 256 + threadIdx.x;          // one float4 of out
  if (blockIdx.x == 0 && threadIdx.x < E_) counts[threadIdx.x] = 0;
  if (idx == 0) out[(size_t)T_ * D_] = 0.0f;         // router aux loss (eval mode)
  int dq = idx & (D_ / 4 - 1);
  f32x4 b = *(const f32x4*)(bias + dq * 4);
  *(f32x4*)(out + (size_t)idx * 4) = b;
}

// one block per token: logits, top-2 + softmax, build expert lists, x -> bf16
__global__ __launch_bounds__(256) void router_kernel(
    const float* __restrict__ x, const float* __restrict__ wg,
    u16* __restrict__ xb, int* __restrict__ lists, float* __restrict__ gates,
    int* __restrict__ counts)
{
  int t = blockIdx.x;
  int tid = threadIdx.x;
  const float* xr = x + (size_t)t * D_;
  float acc[E_];
#pragma unroll
  for (int e = 0; e < E_; ++e) acc[e] = 0.f;
#pragma unroll
  for (int i = 0; i < D_ / 256; ++i) {
    int d = tid + 256 * i;
    float xv = xr[d];
    xb[(size_t)t * D_ + d] = f2bf(xv);
#pragma unroll
    for (int e = 0; e < E_; ++e) acc[e] += xv * wg[e * D_ + d];
  }
#pragma unroll
  for (int off = 32; off >= 1; off >>= 1)
#pragma unroll
    for (int e = 0; e < E_; ++e) acc[e] += __shfl_down(acc[e], off);

  __shared__ float red[4][E_];
  int w = tid >> 6, lane = tid & 63;
  if (lane == 0)
#pragma unroll
    for (int e = 0; e < E_; ++e) red[w][e] = acc[e];
  __syncthreads();
  if (tid == 0) {
    float v0 = -1e30f, v1 = -1e30f; int e0 = 0, e1 = 0;
#pragma unroll
    for (int e = 0; e < E_; ++e) {
      float v = red[0][e] + red[1][e] + red[2][e] + red[3][e];
      if (v > v0)      { v1 = v0; e1 = e0; v0 = v; e0 = e; }
      else if (v > v1) { v1 = v;  e1 = e; }
    }
    float g1 = expf(v1 - v0);
    float inv = 1.f / (1.f + g1);
    float g0 = inv; g1 *= inv;
    int s0 = atomicAdd(&counts[e0], 1);
    lists[e0 * T_ + s0] = t * 2 + 0;
    gates[t * 2 + 0] = g0;
    int s1 = atomicAdd(&counts[e1], 1);
    lists[e1 * T_ + s1] = t * 2 + 1;
    gates[t * 2 + 1] = g1;
  }
}

// grouped GEMM1 + SiLU-GLU epilogue. 128 token-rows x 128 cols (64 h1 + 64 h2
// interleaved per 32-col group so pairs land in same lane). 2x2 waves of 64x64.
__global__ __launch_bounds__(256) void gemm1_kernel(
    const u16* __restrict__ xb, const float* __restrict__ w_in,
    const int* __restrict__ lists, const int* __restrict__ counts,
    u16* __restrict__ a_buf)
{
  int e = blockIdx.z, bm = blockIdx.y, bn = blockIdx.x;
  int Ne = counts[e];
  if (bm * 128 >= Ne) return;

  __shared__ __align__(16) u16 As[128 * 64];
  __shared__ __align__(16) u16 Bs[128 * 64];

  int tid = threadIdx.x, w = tid >> 6, lane = tid & 63;
  int sr = tid >> 3, sc = tid & 7;                 // staging: row base, 8-elem chunk

  const u16* aptr[4];
#pragma unroll
  for (int i = 0; i < 4; ++i) {
    int gr = bm * 128 + sr + 32 * i;
    aptr[i] = (gr < Ne) ? (xb + (size_t)(lists[e * T_ + gr] >> 1) * D_ + sc * 8) : nullptr;
  }
  const float* bptr[4];
#pragma unroll
  for (int i = 0; i < 4; ++i) {
    int r = sr + 32 * i;
    // Bs row r -> h-column: [0,32)=h1(wc0) [32,64)=h2(wc0) [64,96)=h1(wc1) [96,128)=h2(wc1)
    int o = bn * 64 + ((r >> 5) & 1) * H_ + (r >> 6) * 32 + (r & 31);
    bptr[i] = w_in + (size_t)e * (2 * H_) * D_ + (size_t)o * D_ + sc * 8;
  }

  s16x8 areg[4]; f32x4 b0[4], b1[4];
#define LOADS1(K) { _Pragma("unroll") for (int i = 0; i < 4; ++i) { \
                      s16x8 v = {0,0,0,0,0,0,0,0}; \
                      if (aptr[i]) v = *(const s16x8*)(aptr[i] + (K)); areg[i] = v; } \
                    _Pragma("unroll") for (int i = 0; i < 4; ++i) { \
                      b0[i] = *(const f32x4*)(bptr[i] + (K)); \
                      b1[i] = *(const f32x4*)(bptr[i] + (K) + 4); } }

  f32x4 acc[4][4];
#pragma unroll
  for (int m = 0; m < 4; ++m)
#pragma unroll
    for (int n = 0; n < 4; ++n) acc[m][n] = (f32x4){0.f, 0.f, 0.f, 0.f};

  int wr = (w >> 1) * 64, wc = (w & 1) * 64, lrow = lane & 15, g = lane >> 4;

  LOADS1(0);
  for (int kt = 0; kt < D_ / BK; ++kt) {
#pragma unroll
    for (int i = 0; i < 4; ++i) *(s16x8*)(&As[slot(sr + 32 * i, sc)]) = areg[i];
#pragma unroll
    for (int i = 0; i < 4; ++i) *(s16x8*)(&Bs[slot(sr + 32 * i, sc)]) = cvt8(b0[i], b1[i]);
    __syncthreads();
    if (kt + 1 < D_ / BK) LOADS1((kt + 1) * BK);   // prefetch: hides under MFMA phase
#pragma unroll
    for (int ks = 0; ks < 2; ++ks) {
      int ch = ks * 4 + g;
      s16x8 af[4], bf[4];
#pragma unroll
      for (int m = 0; m < 4; ++m) af[m] = *(const s16x8*)(&As[slot(wr + m * 16 + lrow, ch)]);
#pragma unroll
      for (int n = 0; n < 4; ++n) bf[n] = *(const s16x8*)(&Bs[slot(wc + n * 16 + lrow, ch)]);
#pragma unroll
      for (int m = 0; m < 4; ++m)
#pragma unroll
        for (int n = 0; n < 4; ++n)
          acc[m][n] = __builtin_amdgcn_mfma_f32_16x16x32_bf16(af[m], bf[n], acc[m][n], 0, 0, 0);
    }
    __syncthreads();
  }
  // epilogue: a = silu(h1)*h2 -> bf16
  int lcol = lane & 15, lr4 = (lane >> 4) * 4;
  int wcc = (w & 1) * 32;
#pragma unroll
  for (int m = 0; m < 4; ++m)
#pragma unroll
    for (int q = 0; q < 4; ++q) {
      int row = bm * 128 + wr + m * 16 + lr4 + q;
      if (row < Ne) {
#pragma unroll
        for (int n = 0; n < 2; ++n) {
          float h1 = acc[m][n][q], h2 = acc[m][n + 2][q];
          float a = (h1 / (1.f + __expf(-h1))) * h2;
          a_buf[((size_t)e * T_ + row) * H_ + bn * 64 + wcc + n * 16 + lcol] = f2bf(a);
        }
      }
    }
}

// grouped GEMM2: out[t] += gate * (a_row . w_out[e]^T)  (atomic, bias pre-filled)
__global__ __launch_bounds__(256) void gemm2_kernel(
    const u16* __restrict__ a_buf, const float* __restrict__ w_out,
    const int* __restrict__ lists, const int* __restrict__ counts,
    const float* __restrict__ gates, float* __restrict__ out)
{
  int e = blockIdx.z, bm = blockIdx.y, bn = blockIdx.x;
  int Ne = counts[e];
  if (bm * 128 >= Ne) return;

  __shared__ __align__(16) u16 As[128 * 64];
  __shared__ __align__(16) u16 Bs[128 * 64];

  int tid = threadIdx.x, w = tid >> 6, lane = tid & 63;
  int sr = tid >> 3, sc = tid & 7;

  const u16* aptr[4];
#pragma unroll
  for (int i = 0; i < 4; ++i) {
    int gr = bm * 128 + sr + 32 * i;
    aptr[i] = (gr < Ne) ? (a_buf + ((size_t)e * T_ + gr) * H_ + sc * 8) : nullptr;
  }
  const float* bptr[4];
#pragma unroll
  for (int i = 0; i < 4; ++i) {
    int r = sr + 32 * i;
    bptr[i] = w_out + (size_t)e * D_ * H_ + (size_t)(bn * 128 + r) * H_ + sc * 8;
  }

  s16x8 areg[4]; f32x4 b0[4], b1[4];
#define LOADS2(K) { _Pragma("unroll") for (int i = 0; i < 4; ++i) { \
                      s16x8 v = {0,0,0,0,0,0,0,0}; \
                      if (aptr[i]) v = *(const s16x8*)(aptr[i] + (K)); areg[i] = v; } \
                    _Pragma("unroll") for (int i = 0; i < 4; ++i) { \
                      b0[i] = *(const f32x4*)(bptr[i] + (K)); \
                      b1[i] = *(const f32x4*)(bptr[i] + (K) + 4); } }

  f32x4 acc[4][4];
#pragma unroll
  for (int m = 0; m < 4; ++m)
#pragma unroll
    for (int n = 0; n < 4; ++n) acc[m][n] = (f32x4){0.f, 0.f, 0.f, 0.f};

  int wr = (w >> 1) * 64, wc = (w & 1) * 64, lrow = lane & 15, g = lane >> 4;

  LOADS2(0);
  for (int kt = 0; kt < H_ / BK; ++kt) {
#pragma unroll
    for (int i = 0; i < 4; ++i) *(s16x8*)(&As[slot(sr + 32 * i, sc)]) = areg[i];
#pragma unroll
    for (int i = 0; i < 4; ++i) *(s16x8*)(&Bs[slot(sr + 32 * i, sc)]) = cvt8(b0[i], b1[i]);
    __syncthreads();
    if (kt + 1 < H_ / BK) LOADS2((kt + 1) * BK);
#pragma unroll
    for (int ks = 0; ks < 2; ++ks) {
      int ch = ks * 4 + g;
      s16x8 af[4], bf[4];
#pragma unroll
      for (int m = 0; m < 4; ++m) af[m] = *(const s16x8*)(&As[slot(wr + m * 16 + lrow, ch)]);
#pragma unroll
      for (int n = 0; n < 4; ++n) bf[n] = *(const s16x8*)(&Bs[slot(wc + n * 16 + lrow, ch)]);
#pragma unroll
      for (int m = 0; m < 4; ++m)
#pragma unroll
        for (int n = 0; n < 4; ++n)
          acc[m][n] = __builtin_amdgcn_mfma_f32_16x16x32_bf16(af[m], bf[n], acc[m][n], 0, 0, 0);
    }
    __syncthreads();
  }
  int lcol = lane & 15, lr4 = (lane >> 4) * 4;
#pragma unroll
  for (int m = 0; m < 4; ++m)
#pragma unroll
    for (int q = 0; q < 4; ++q) {
      int row = bm * 128 + wr + m * 16 + lr4 + q;
      if (row < Ne) {
        int p = lists[e * T_ + row];
        float gt = gates[p];
        int t = p >> 1;
#pragma unroll
        for (int n = 0; n < 4; ++n)
          atomicAdd(&out[(size_t)t * D_ + bn * 128 + wc + n * 16 + lcol], gt * acc[m][n][q]);
      }
    }
}

extern "C" void kernel_launch(void* const* d_in, const int* in_sizes, int n_in,
                              void* d_out, int out_size, void* d_ws, size_t ws_size,
                              hipStream_t stream)
{
  const float* x      = (const float*)d_in[0];
  const float* w_gate = (const float*)d_in[1];
  const float* w_in   = (const float*)d_in[2];
  const float* w_out  = (const float*)d_in[3];
  const float* bias   = (const float*)d_in[4];
  float* out = (float*)d_out;

  char* ws = (char*)d_ws;
  u16*   xb     = (u16*)(ws);
  u16*   a_buf  = (u16*)(ws + 8388608);
  int*   lists  = (int*)(ws + 41943040);
  float* gates  = (float*)(ws + 42008576);
  int*   counts = (int*)(ws + 42024960);

  init_kernel<<<T_ * D_ / 4 / 256, 256, 0, stream>>>(bias, out, counts);
  router_kernel<<<T_, 256, 0, stream>>>(x, w_gate, xb, lists, gates, counts);
  dim3 g1(H_ / 64, 16, E_);
  gemm1_kernel<<<g1, 256, 0, stream>>>(xb, w_in, lists, counts, a_buf);
  dim3 g2(D_ / 128, 16, E_);
  gemm2_kernel<<<g2, 256, 0, stream>>>(a_buf, w_out, lists, counts, gates, out);
}

// Round 3
// 232.474 us; speedup vs baseline: 1.3274x; 1.3203x over previous
//
#include <hip/hip_runtime.h>

#define E_    8
#define D_    2048
#define H_    1024
#define T_    2048   // B*L tokens
#define BK    64

using u16   = unsigned short;
using s16x8 = __attribute__((ext_vector_type(8))) short;
using f32x4 = __attribute__((ext_vector_type(4))) float;

__device__ __forceinline__ u16 f2bf(float f) {
  union { float f; unsigned u; } v; v.f = f;
  unsigned r = v.u + 0x7fffu + ((v.u >> 16) & 1u);   // RNE
  return (u16)(r >> 16);
}
__device__ __forceinline__ s16x8 cvt8(f32x4 a, f32x4 b) {
  s16x8 o;
  o[0]=(short)f2bf(a.x); o[1]=(short)f2bf(a.y); o[2]=(short)f2bf(a.z); o[3]=(short)f2bf(a.w);
  o[4]=(short)f2bf(b.x); o[5]=(short)f2bf(b.y); o[6]=(short)f2bf(b.z); o[7]=(short)f2bf(b.w);
  return o;
}
// swizzled LDS slot (elem index) for (row, 8-elem chunk) in a [*][64] bf16 tile
__device__ __forceinline__ int slot(int r, int c) { return r * 64 + ((c ^ (r & 7)) << 3); }

// ---------------- workspace layout (bytes) ----------------
// xb     : T*D bf16     =  8,388,608  @ 0
// a_buf  : E*T*H bf16   = 33,554,432  @ 8,388,608
// lists  : E*T int      =     65,536  @ 41,943,040
// gates  : T*K f32      =     16,384  @ 42,008,576
// counts : E int        =         32  @ 42,024,960

__global__ __launch_bounds__(256) void init_kernel(
    const float* __restrict__ bias, float* __restrict__ out, int* __restrict__ counts)
{
  int idx = blockIdx.x * 256 + threadIdx.x;          // one float4 of out
  if (blockIdx.x == 0 && threadIdx.x < E_) counts[threadIdx.x] = 0;
  if (idx == 0) out[(size_t)T_ * D_] = 0.0f;         // router aux loss (eval mode)
  int dq = idx & (D_ / 4 - 1);
  f32x4 b = *(const f32x4*)(bias + dq * 4);
  *(f32x4*)(out + (size_t)idx * 4) = b;
}

// one block per token: logits, top-2 + softmax, build expert lists, x -> bf16
__global__ __launch_bounds__(256) void router_kernel(
    const float* __restrict__ x, const float* __restrict__ wg,
    u16* __restrict__ xb, int* __restrict__ lists, float* __restrict__ gates,
    int* __restrict__ counts)
{
  int t = blockIdx.x;
  int tid = threadIdx.x;
  const float* xr = x + (size_t)t * D_;
  float acc[E_];
#pragma unroll
  for (int e = 0; e < E_; ++e) acc[e] = 0.f;
#pragma unroll
  for (int i = 0; i < D_ / 256; ++i) {
    int d = tid + 256 * i;
    float xv = xr[d];
    xb[(size_t)t * D_ + d] = f2bf(xv);
#pragma unroll
    for (int e = 0; e < E_; ++e) acc[e] += xv * wg[e * D_ + d];
  }
#pragma unroll
  for (int off = 32; off >= 1; off >>= 1)
#pragma unroll
    for (int e = 0; e < E_; ++e) acc[e] += __shfl_down(acc[e], off);

  __shared__ float red[4][E_];
  int w = tid >> 6, lane = tid & 63;
  if (lane == 0)
#pragma unroll
    for (int e = 0; e < E_; ++e) red[w][e] = acc[e];
  __syncthreads();
  if (tid == 0) {
    float v0 = -1e30f, v1 = -1e30f; int e0 = 0, e1 = 0;
#pragma unroll
    for (int e = 0; e < E_; ++e) {
      float v = red[0][e] + red[1][e] + red[2][e] + red[3][e];
      if (v > v0)      { v1 = v0; e1 = e0; v0 = v; e0 = e; }
      else if (v > v1) { v1 = v;  e1 = e; }
    }
    float g1 = expf(v1 - v0);
    float inv = 1.f / (1.f + g1);
    float g0 = inv; g1 *= inv;
    int s0 = atomicAdd(&counts[e0], 1);
    lists[e0 * T_ + s0] = t * 2 + 0;
    gates[t * 2 + 0] = g0;
    int s1 = atomicAdd(&counts[e1], 1);
    lists[e1 * T_ + s1] = t * 2 + 1;
    gates[t * 2 + 1] = g1;
  }
}

// grouped GEMM1 + SiLU-GLU. 256 token-rows x 128 B-rows (64 h1 + 64 h2).
// 512 threads = 8 waves (4m x 2n) of 64x64. LDS double-buffered, 1 barrier/K-step.
__global__ __launch_bounds__(512) void gemm1_kernel(
    const u16* __restrict__ xb, const float* __restrict__ w_in,
    const int* __restrict__ lists, const int* __restrict__ counts,
    u16* __restrict__ a_buf)
{
  int e = blockIdx.z, bm = blockIdx.y, bn = blockIdx.x;
  int Ne = counts[e];
  if (bm * 256 >= Ne) return;

  __shared__ __align__(16) u16 As[2][256 * 64];   // 64 KB
  __shared__ __align__(16) u16 Bs[2][128 * 64];   // 32 KB

  int tid = threadIdx.x, w = tid >> 6, lane = tid & 63;
  int sr = tid >> 3, sc = tid & 7;                // A staging: rows sr+64i, chunk sc
  int br = tid >> 2, bc = (tid & 3) * 2;          // B staging: row br, chunks bc,bc+1

  const u16* aptr[4];
#pragma unroll
  for (int i = 0; i < 4; ++i) {
    int gr = bm * 256 + sr + 64 * i;
    aptr[i] = (gr < Ne) ? (xb + (size_t)(lists[e * T_ + gr] >> 1) * D_ + sc * 8) : nullptr;
  }
  // B row br -> w_in row: [0,32)=h1(wv0) [32,64)=h2(wv0) [64,96)=h1(wv1) [96,128)=h2(wv1)
  int o = bn * 64 + ((br >> 5) & 1) * H_ + (br >> 6) * 32 + (br & 31);
  const float* bptr = w_in + (size_t)e * (2 * H_) * D_ + (size_t)o * D_ + bc * 8;

  s16x8 areg[4]; f32x4 bl[4];
#define LOADS1(K) { _Pragma("unroll") for (int i = 0; i < 4; ++i) { \
                      s16x8 v = {0,0,0,0,0,0,0,0}; \
                      if (aptr[i]) v = *(const s16x8*)(aptr[i] + (K)); areg[i] = v; } \
                    _Pragma("unroll") for (int i = 0; i < 4; ++i) \
                      bl[i] = *(const f32x4*)(bptr + (K) + i * 4); }
#define STAGE1(B) { _Pragma("unroll") for (int i = 0; i < 4; ++i) \
                      *(s16x8*)(&As[B][slot(sr + 64 * i, sc)]) = areg[i]; \
                    *(s16x8*)(&Bs[B][slot(br, bc)])     = cvt8(bl[0], bl[1]); \
                    *(s16x8*)(&Bs[B][slot(br, bc + 1)]) = cvt8(bl[2], bl[3]); }

  f32x4 acc[4][4];
#pragma unroll
  for (int m = 0; m < 4; ++m)
#pragma unroll
    for (int n = 0; n < 4; ++n) acc[m][n] = (f32x4){0.f, 0.f, 0.f, 0.f};

  int wr = (w >> 1) * 64, wc = (w & 1) * 64, lrow = lane & 15, g = lane >> 4;

  LOADS1(0);
  STAGE1(0);
  __syncthreads();
  const int NT = D_ / BK;
  for (int kt = 0; kt < NT; ++kt) {
    int cur = kt & 1;
    if (kt + 1 < NT) LOADS1((kt + 1) * BK);       // in flight during compute
#pragma unroll
    for (int ks = 0; ks < 2; ++ks) {
      int ch = ks * 4 + g;
      s16x8 af[4], bf[4];
#pragma unroll
      for (int m = 0; m < 4; ++m) af[m] = *(const s16x8*)(&As[cur][slot(wr + m * 16 + lrow, ch)]);
#pragma unroll
      for (int n = 0; n < 4; ++n) bf[n] = *(const s16x8*)(&Bs[cur][slot(wc + n * 16 + lrow, ch)]);
#pragma unroll
      for (int m = 0; m < 4; ++m)
#pragma unroll
        for (int n = 0; n < 4; ++n)
          acc[m][n] = __builtin_amdgcn_mfma_f32_16x16x32_bf16(af[m], bf[n], acc[m][n], 0, 0, 0);
    }
    if (kt + 1 < NT) {
      STAGE1(cur ^ 1);                             // waits vmcnt for LOADS(kt+1)
      __syncthreads();                             // single barrier per K-step
    }
  }
  // epilogue: a = silu(h1)*h2 -> bf16
  int lcol = lane & 15, lr4 = (lane >> 4) * 4;
  int wcc = (w & 1) * 32;
#pragma unroll
  for (int m = 0; m < 4; ++m)
#pragma unroll
    for (int q = 0; q < 4; ++q) {
      int row = bm * 256 + wr + m * 16 + lr4 + q;
      if (row < Ne) {
#pragma unroll
        for (int n = 0; n < 2; ++n) {
          float h1 = acc[m][n][q], h2 = acc[m][n + 2][q];
          float a = (h1 / (1.f + __expf(-h1))) * h2;
          a_buf[((size_t)e * T_ + row) * H_ + bn * 64 + wcc + n * 16 + lcol] = f2bf(a);
        }
      }
    }
}

// grouped GEMM2: out[t] += gate * (a_row . w_out[e]^T)  (atomic, bias pre-filled)
__global__ __launch_bounds__(512) void gemm2_kernel(
    const u16* __restrict__ a_buf, const float* __restrict__ w_out,
    const int* __restrict__ lists, const int* __restrict__ counts,
    const float* __restrict__ gates, float* __restrict__ out)
{
  int e = blockIdx.z, bm = blockIdx.y, bn = blockIdx.x;
  int Ne = counts[e];
  if (bm * 256 >= Ne) return;

  __shared__ __align__(16) u16 As[2][256 * 64];
  __shared__ __align__(16) u16 Bs[2][128 * 64];

  int tid = threadIdx.x, w = tid >> 6, lane = tid & 63;
  int sr = tid >> 3, sc = tid & 7;
  int br = tid >> 2, bc = (tid & 3) * 2;

  const u16* aptr[4];
#pragma unroll
  for (int i = 0; i < 4; ++i) {
    int gr = bm * 256 + sr + 64 * i;
    aptr[i] = (gr < Ne) ? (a_buf + ((size_t)e * T_ + gr) * H_ + sc * 8) : nullptr;
  }
  const float* bptr = w_out + (size_t)e * D_ * H_ + (size_t)(bn * 128 + br) * H_ + bc * 8;

  s16x8 areg[4]; f32x4 bl[4];
#define LOADS2(K) { _Pragma("unroll") for (int i = 0; i < 4; ++i) { \
                      s16x8 v = {0,0,0,0,0,0,0,0}; \
                      if (aptr[i]) v = *(const s16x8*)(aptr[i] + (K)); areg[i] = v; } \
                    _Pragma("unroll") for (int i = 0; i < 4; ++i) \
                      bl[i] = *(const f32x4*)(bptr + (K) + i * 4); }
#define STAGE2(B) { _Pragma("unroll") for (int i = 0; i < 4; ++i) \
                      *(s16x8*)(&As[B][slot(sr + 64 * i, sc)]) = areg[i]; \
                    *(s16x8*)(&Bs[B][slot(br, bc)])     = cvt8(bl[0], bl[1]); \
                    *(s16x8*)(&Bs[B][slot(br, bc + 1)]) = cvt8(bl[2], bl[3]); }

  f32x4 acc[4][4];
#pragma unroll
  for (int m = 0; m < 4; ++m)
#pragma unroll
    for (int n = 0; n < 4; ++n) acc[m][n] = (f32x4){0.f, 0.f, 0.f, 0.f};

  int wr = (w >> 1) * 64, wc = (w & 1) * 64, lrow = lane & 15, g = lane >> 4;

  LOADS2(0);
  STAGE2(0);
  __syncthreads();
  const int NT = H_ / BK;
  for (int kt = 0; kt < NT; ++kt) {
    int cur = kt & 1;
    if (kt + 1 < NT) LOADS2((kt + 1) * BK);
#pragma unroll
    for (int ks = 0; ks < 2; ++ks) {
      int ch = ks * 4 + g;
      s16x8 af[4], bf[4];
#pragma unroll
      for (int m = 0; m < 4; ++m) af[m] = *(const s16x8*)(&As[cur][slot(wr + m * 16 + lrow, ch)]);
#pragma unroll
      for (int n = 0; n < 4; ++n) bf[n] = *(const s16x8*)(&Bs[cur][slot(wc + n * 16 + lrow, ch)]);
#pragma unroll
      for (int m = 0; m < 4; ++m)
#pragma unroll
        for (int n = 0; n < 4; ++n)
          acc[m][n] = __builtin_amdgcn_mfma_f32_16x16x32_bf16(af[m], bf[n], acc[m][n], 0, 0, 0);
    }
    if (kt + 1 < NT) {
      STAGE2(cur ^ 1);
      __syncthreads();
    }
  }
  int lcol = lane & 15, lr4 = (lane >> 4) * 4;
#pragma unroll
  for (int m = 0; m < 4; ++m)
#pragma unroll
    for (int q = 0; q < 4; ++q) {
      int row = bm * 256 + wr + m * 16 + lr4 + q;
      if (row < Ne) {
        int p = lists[e * T_ + row];
        float gt = gates[p];
        int t = p >> 1;
#pragma unroll
        for (int n = 0; n < 4; ++n)
          atomicAdd(&out[(size_t)t * D_ + bn * 128 + wc + n * 16 + lcol], gt * acc[m][n][q]);
      }
    }
}

extern "C" void kernel_launch(void* const* d_in, const int* in_sizes, int n_in,
                              void* d_out, int out_size, void* d_ws, size_t ws_size,
                              hipStream_t stream)
{
  const float* x      = (const float*)d_in[0];
  const float* w_gate = (const float*)d_in[1];
  const float* w_in   = (const float*)d_in[2];
  const float* w_out  = (const float*)d_in[3];
  const float* bias   = (const float*)d_in[4];
  float* out = (float*)d_out;

  char* ws = (char*)d_ws;
  u16*   xb     = (u16*)(ws);
  u16*   a_buf  = (u16*)(ws + 8388608);
  int*   lists  = (int*)(ws + 41943040);
  float* gates  = (float*)(ws + 42008576);
  int*   counts = (int*)(ws + 42024960);

  init_kernel<<<T_ * D_ / 4 / 256, 256, 0, stream>>>(bias, out, counts);
  router_kernel<<<T_, 256, 0, stream>>>(x, w_gate, xb, lists, gates, counts);
  dim3 g1(H_ / 64, 8, E_);     // (16, 8, 8): ~256 active blocks (2 bm-tiles/expert)
  gemm1_kernel<<<g1, 512, 0, stream>>>(xb, w_in, lists, counts, a_buf);
  dim3 g2(D_ / 128, 8, E_);    // (16, 8, 8)
  gemm2_kernel<<<g2, 512, 0, stream>>>(a_buf, w_out, lists, counts, gates, out);
}